// Round 9
// baseline (259.333 us; speedup 1.0000x reference)
//
#include <hip/hip_runtime.h>
#include <hip/hip_fp16.h>

#define NN 1024
#define BATCH 8
#define CDIM 16
#define NITER 50           // full 50-iteration trajectory (round-7 lesson)
#define CAPC 512           // coarse candidates per row (margin 4.0, built at t=2)
#define CAPF 160           // fine candidates per row (margin 0.6, built at t=6)
#define NPERS 47           // persistent iterations t=3..49

// eps = 0.05^2 = 0.0025
// K_SCALE = 1/(eps*ln2); EPS_LN2 = eps*ln2; log2(1/1024) = -10 exactly.
static constexpr float K_SCALE = 577.0780163555854f;
static constexpr float EPS_LN2 = 0.0017328679513998632f;
static constexpr float MARGIN_T = 0.6f * 577.0780163555854f;   // fine margin (t-units)
static constexpr float MARGIN_C = 4.0f * 577.0780163555854f;   // coarse margin (t-units)

#if __has_builtin(__builtin_amdgcn_exp2f)
#define EXP2F(x) __builtin_amdgcn_exp2f(x)
#else
#define EXP2F(x) exp2f(x)
#endif
#if __has_builtin(__builtin_amdgcn_logf)
#define LOG2F(x) __builtin_amdgcn_logf(x)
#else
#define LOG2F(x) log2f(x)
#endif

// 4 cost matrices in fp16: 0 = C_xy, 1 = C_yx, 2 = C_xx, 3 = C_yy   (64 MiB)
__device__ __half g_C16[4][BATCH][NN][NN];
// potentials for t<=2: [parity][which: 0=f,1=g,2=p,3=q][batch][row]
__device__ float g_pot[2][4][BATCH][NN];
// write-once per-iteration potentials for the persistent phase:
// g_seq[k] = potentials AFTER iteration t = k+2  (g_seq[0] written by t=2 launch)
__device__ float g_seq[NPERS + 1][4][BATCH][NN];   // ~6.3 MiB
__device__ float g_mse_part[128];
// candidate lists: packed (j << 16) | fp16-bits(C_ij), flat [pass][batch][row][cap]
__device__ __align__(16) unsigned g_cand_c[4 * BATCH * NN * CAPC];  // ~67 MiB
__device__ unsigned g_cnt_c[4 * BATCH * NN];
__device__ __align__(16) unsigned g_cand_f[4 * BATCH * NN * CAPF];  // ~21 MiB
__device__ unsigned g_cnt_f[4 * BATCH * NN];
// per-component, per-iteration barrier arrival counters (reset every call)
__device__ unsigned g_bar[24][64];

// Zero barrier counters + per-block MSE partials (no atomics -> deterministic).
__global__ __launch_bounds__(256) void init_mse_kernel(const float* __restrict__ a,
                                                       const float* __restrict__ b) {
    int tid = threadIdx.x;
    int idx = blockIdx.x * 256 + tid;
    if (idx < 24 * 64) (&g_bar[0][0])[idx] = 0u;

    const int total = BATCH * NN * CDIM;  // 131072
    float acc = 0.0f;
    for (int i = idx; i < total; i += gridDim.x * 256) {
        float d = a[i] - b[i];
        acc = fmaf(d, d, acc);
    }
    #pragma unroll
    for (int off = 32; off; off >>= 1) acc += __shfl_xor(acc, off, 64);
    __shared__ float red[4];
    int lane = tid & 63, wid = tid >> 6;
    if (lane == 0) red[wid] = acc;
    __syncthreads();
    if (tid == 0) g_mse_part[blockIdx.x] = red[0] + red[1] + red[2] + red[3];
}

struct alignas(8) H4 { __half2 a, b; };

// Gram-form cost, FUSED with iteration t=0 (h==0, so the softmin over each
// full row needs only a block reduction over this block's 256x4 values,
// computed from the SAME fp16-rounded C values the dense path would read).
// Writes t=0 output (0.5 * softmin) to g_pot[1].
__global__ __launch_bounds__(256) void cost_kernel(const float* __restrict__ x,
                                                   const float* __restrict__ y) {
    int bid = blockIdx.x;
    int m = bid >> 9;
    int b = (bid >> 6) & 7;
    int ig = bid & 63;
    const float* X = (m == 1 || m == 3) ? y : x;
    const float* Y = (m == 0 || m == 3) ? y : x;
    int tid = threadIdx.x;
    int lane = tid & 63, wid = tid >> 6;
    int j0 = tid * 4;

    __shared__ float xs[16 * CDIM];
    __shared__ float x2s[16];
    __shared__ float redm[4], reds[4];
    xs[tid] = X[(size_t)(b * NN + ig * 16) * CDIM + tid];
    __syncthreads();
    if (tid < 16) {
        float a = 0.0f;
        #pragma unroll
        for (int k = 0; k < CDIM; ++k) a = fmaf(xs[tid * CDIM + k], xs[tid * CDIM + k], a);
        x2s[tid] = 0.5f * a;
    }

    float yr[4][16];
    const float4* Y4 = reinterpret_cast<const float4*>(Y + (size_t)(b * NN + j0) * CDIM);
    #pragma unroll
    for (int rr = 0; rr < 4; ++rr) {
        #pragma unroll
        for (int q = 0; q < 4; ++q) {
            float4 v = Y4[rr * 4 + q];
            yr[rr][q * 4 + 0] = v.x; yr[rr][q * 4 + 1] = v.y;
            yr[rr][q * 4 + 2] = v.z; yr[rr][q * 4 + 3] = v.w;
        }
    }
    float y2h[4];
    #pragma unroll
    for (int rr = 0; rr < 4; ++rr) {
        float acc = 0.0f;
        #pragma unroll
        for (int k = 0; k < CDIM; ++k) acc = fmaf(yr[rr][k], yr[rr][k], acc);
        y2h[rr] = 0.5f * acc;
    }
    __syncthreads();

    #pragma unroll 1
    for (int r = 0; r < 16; ++r) {
        float xv[CDIM];
        #pragma unroll
        for (int k = 0; k < CDIM; ++k) xv[k] = xs[r * CDIM + k];
        float x2h = x2s[r];

        float acc[4];
        #pragma unroll
        for (int rr = 0; rr < 4; ++rr) {
            float a = x2h + y2h[rr];
            #pragma unroll
            for (int k = 0; k < CDIM; ++k) a = fmaf(xv[k], -yr[rr][k], a);
            acc[rr] = a;
        }
        __half hcv[4];
        float tv[4];
        #pragma unroll
        for (int rr = 0; rr < 4; ++rr) {
            hcv[rr] = __float2half_rn(acc[rr]);
            tv[rr] = __half2float(hcv[rr]) * (-K_SCALE);
        }
        H4 out;
        out.a = __halves2half2(hcv[0], hcv[1]);
        out.b = __halves2half2(hcv[2], hcv[3]);
        int i = ig * 16 + r;
        *reinterpret_cast<H4*>(&g_C16[m][b][i][j0]) = out;

        // fused t=0 softmin (h == 0)
        float mx4 = fmaxf(fmaxf(tv[0], tv[1]), fmaxf(tv[2], tv[3]));
        #pragma unroll
        for (int off = 32; off; off >>= 1) mx4 = fmaxf(mx4, __shfl_xor(mx4, off, 64));
        if (lane == 0) redm[wid] = mx4;
        __syncthreads();
        float mx = fmaxf(fmaxf(redm[0], redm[1]), fmaxf(redm[2], redm[3]));
        float s4 = EXP2F(tv[0] - mx) + EXP2F(tv[1] - mx)
                 + EXP2F(tv[2] - mx) + EXP2F(tv[3] - mx);
        #pragma unroll
        for (int off = 32; off; off >>= 1) s4 += __shfl_xor(s4, off, 64);
        if (lane == 0) reds[wid] = s4;
        __syncthreads();
        if (tid == 0) {
            float stot = reds[0] + reds[1] + reds[2] + reds[3];
            g_pot[1][m][b][i] = 0.5f * (-EPS_LN2 * (mx - 10.0f + LOG2F(stot)));
        }
        __syncthreads();
    }
}

__device__ inline float2 cvt2(unsigned int u) {
    __half2 h;
    *reinterpret_cast<unsigned int*>(&h) = u;
    return __half22float2(h);
}

// Dense wave-per-row softmin iteration (t=1, t=2). BUILD (t=2 only) emits the
// coarse candidate set and writes its output to g_seq[0] (persist input).
template <bool BUILD>
__global__ __launch_bounds__(256) void iter_kernel_t(int parity) {
    int bid = blockIdx.x;
    int p = bid >> 9;
    int b = (bid >> 6) & 7;
    int rg = bid & 63;
    int hsel = (p == 0) ? 1 : (p == 1) ? 0 : p;

    int tid = threadIdx.x;
    int lane = tid & 63, wid = tid >> 6;

    const float* __restrict__ hin  = g_pot[parity][hsel][b];
    const float* __restrict__ oldp = g_pot[parity][p][b];
    float* __restrict__ outp = BUILD ? &g_seq[0][p][b][0] : &g_pot[parity ^ 1][p][b][0];

    float hs[16];
    {
        const float4* h4 = reinterpret_cast<const float4*>(hin);
        float4 a0 = h4[lane * 2], a1 = h4[lane * 2 + 1];
        float4 b0 = h4[128 + lane * 2], b1 = h4[128 + lane * 2 + 1];
        hs[0] = a0.x * K_SCALE;  hs[1] = a0.y * K_SCALE;
        hs[2] = a0.z * K_SCALE;  hs[3] = a0.w * K_SCALE;
        hs[4] = a1.x * K_SCALE;  hs[5] = a1.y * K_SCALE;
        hs[6] = a1.z * K_SCALE;  hs[7] = a1.w * K_SCALE;
        hs[8]  = b0.x * K_SCALE; hs[9]  = b0.y * K_SCALE;
        hs[10] = b0.z * K_SCALE; hs[11] = b0.w * K_SCALE;
        hs[12] = b1.x * K_SCALE; hs[13] = b1.y * K_SCALE;
        hs[14] = b1.z * K_SCALE; hs[15] = b1.w * K_SCALE;
    }

    #pragma unroll
    for (int r = 0; r < 4; ++r) {
        int i = rg * 16 + wid * 4 + r;
        const uint4* crow = reinterpret_cast<const uint4*>(&g_C16[p][b][i][0]);
        uint4 ca = crow[lane];
        uint4 cb = crow[64 + lane];

        float t[16];
        {
            float2 f;
            f = cvt2(ca.x); t[0] = fmaf(f.x, -K_SCALE, hs[0]);  t[1] = fmaf(f.y, -K_SCALE, hs[1]);
            f = cvt2(ca.y); t[2] = fmaf(f.x, -K_SCALE, hs[2]);  t[3] = fmaf(f.y, -K_SCALE, hs[3]);
            f = cvt2(ca.z); t[4] = fmaf(f.x, -K_SCALE, hs[4]);  t[5] = fmaf(f.y, -K_SCALE, hs[5]);
            f = cvt2(ca.w); t[6] = fmaf(f.x, -K_SCALE, hs[6]);  t[7] = fmaf(f.y, -K_SCALE, hs[7]);
            f = cvt2(cb.x); t[8] = fmaf(f.x, -K_SCALE, hs[8]);  t[9] = fmaf(f.y, -K_SCALE, hs[9]);
            f = cvt2(cb.y); t[10] = fmaf(f.x, -K_SCALE, hs[10]); t[11] = fmaf(f.y, -K_SCALE, hs[11]);
            f = cvt2(cb.z); t[12] = fmaf(f.x, -K_SCALE, hs[12]); t[13] = fmaf(f.y, -K_SCALE, hs[13]);
            f = cvt2(cb.w); t[14] = fmaf(f.x, -K_SCALE, hs[14]); t[15] = fmaf(f.y, -K_SCALE, hs[15]);
        }

        float mx = t[0];
        #pragma unroll
        for (int k = 1; k < 16; ++k) mx = fmaxf(mx, t[k]);
        #pragma unroll
        for (int off = 32; off; off >>= 1) mx = fmaxf(mx, __shfl_xor(mx, off, 64));

        float s = 0.0f;
        #pragma unroll
        for (int k = 0; k < 16; ++k) s += EXP2F(t[k] - mx);
        #pragma unroll
        for (int off = 32; off; off >>= 1) s += __shfl_xor(s, off, 64);

        if (lane == 0) {
            float res = -EPS_LN2 * (mx - 10.0f + LOG2F(s));
            outp[i] = 0.5f * (oldp[i] + res);
        }

        if (BUILD) {
            size_t rowid = (size_t)((p * BATCH + b) * NN + i);
            float thr = mx - MARGIN_C;
            int c = 0;
            #pragma unroll
            for (int k = 0; k < 16; ++k) c += (t[k] >= thr) ? 1 : 0;
            int incl = c;
            #pragma unroll
            for (int off = 1; off < 64; off <<= 1) {
                int v = __shfl_up(incl, off, 64);
                if (lane >= off) incl += v;
            }
            int excl = incl - c;
            int total = __shfl(incl, 63, 64);
            if (lane == 0) g_cnt_c[rowid] = (unsigned)(total < CAPC ? total : CAPC);

            union U4 { uint4 q; unsigned w[4]; } A, B2;
            A.q = ca; B2.q = cb;
            unsigned* dst = &g_cand_c[rowid * CAPC];
            int slot = excl;
            #pragma unroll
            for (int k = 0; k < 16; ++k) {
                if (t[k] >= thr) {
                    if (slot < CAPC) {
                        unsigned hb = (k < 8) ? A.w[k >> 1] : B2.w[(k - 8) >> 1];
                        hb = (hb >> ((k & 1) * 16)) & 0xffffu;
                        unsigned j = (k < 8) ? (unsigned)(lane * 8 + k)
                                             : (unsigned)(512 + lane * 8 + (k - 8));
                        dst[slot] = (j << 16) | hb;
                    }
                    ++slot;
                }
            }
        }
    }
}

// Persistent sparse phase: iterations t=3..49 in ONE launch.
// Grid 512 blocks (2/CU, co-resident). Per-component barriers: {f,g}xbatch =
// 32 blocks, {p}/{q}xbatch = 16. Coherence protocol: write-once buffers
// g_seq[k+1]; writers publish via atomicExch (device-scope, memory-side,
// bypasses incoherent per-XCD L2s); readers use normal loads (fresh address ->
// clean fill). Old potential carried in a register. No __threadfence -> the
// L2-cached candidate lists are never invalidated.
__global__ __launch_bounds__(256, 2) void persist_kernel() {
    int bid = blockIdx.x;
    int p = bid >> 7;            // 0..3
    int b = (bid >> 4) & 7;      // 0..7
    int rg = bid & 15;           // 0..15
    int hsel = (p == 0) ? 1 : (p == 1) ? 0 : p;
    int comp; unsigned nb;
    if (p <= 1)      { comp = b;      nb = 32u; }
    else if (p == 2) { comp = 8 + b;  nb = 16u; }
    else             { comp = 16 + b; nb = 16u; }

    int tid = threadIdx.x;
    int lane = tid & 63, wid = tid >> 6;
    int c = lane & 3;
    int i = rg * 64 + wid * 16 + (lane >> 2);
    size_t rowid = (size_t)((p * BATCH + b) * NN + i);

    __shared__ float h2[NN];
    float myold = g_seq[0][p][b][i];   // t=2 output (cross-launch, coherent)

    for (int k = 0; k < NPERS; ++k) {
        // stage h (scaled) for this iteration; g_seq[k] fully published
        {
            const float4* h4 = reinterpret_cast<const float4*>(&g_seq[k][hsel][b][0]);
            float4 v = h4[tid];
            v.x *= K_SCALE; v.y *= K_SCALE; v.z *= K_SCALE; v.w *= K_SCALE;
            reinterpret_cast<float4*>(h2)[tid] = v;
        }
        __syncthreads();

        bool coarse = (k <= 3);
        const unsigned* __restrict__ candsrc = coarse ? g_cand_c : g_cand_f;
        const int cap = coarse ? CAPC : CAPF;
        int cnt = (int)(coarse ? g_cnt_c[rowid] : g_cnt_f[rowid]);
        const uint4* __restrict__ cd4 =
            reinterpret_cast<const uint4*>(candsrc + rowid * cap);

        float m = -3.0e38f;
        float s = 0.0f;
        int nstep = (cnt + 15) >> 4;
        for (int kk = 0; kk < nstep; ++kk) {
            int base = kk * 16 + c * 4;
            uint4 u = cd4[kk * 4 + c];
            __half hh;
            *reinterpret_cast<unsigned short*>(&hh) = (unsigned short)(u.x & 0xffffu);
            float t0 = fmaf(__half2float(hh), -K_SCALE, h2[(u.x >> 16) & 1023]);
            *reinterpret_cast<unsigned short*>(&hh) = (unsigned short)(u.y & 0xffffu);
            float t1 = fmaf(__half2float(hh), -K_SCALE, h2[(u.y >> 16) & 1023]);
            *reinterpret_cast<unsigned short*>(&hh) = (unsigned short)(u.z & 0xffffu);
            float t2 = fmaf(__half2float(hh), -K_SCALE, h2[(u.z >> 16) & 1023]);
            *reinterpret_cast<unsigned short*>(&hh) = (unsigned short)(u.w & 0xffffu);
            float t3 = fmaf(__half2float(hh), -K_SCALE, h2[(u.w >> 16) & 1023]);
            t0 = (base + 0 < cnt) ? t0 : -3.0e38f;
            t1 = (base + 1 < cnt) ? t1 : -3.0e38f;
            t2 = (base + 2 < cnt) ? t2 : -3.0e38f;
            t3 = (base + 3 < cnt) ? t3 : -3.0e38f;
            float sm = fmaxf(fmaxf(t0, t1), fmaxf(t2, t3));
            float nm = fmaxf(m, sm);
            s = s * EXP2F(m - nm) + EXP2F(t0 - nm) + EXP2F(t1 - nm)
                                  + EXP2F(t2 - nm) + EXP2F(t3 - nm);
            m = nm;
        }
        #pragma unroll
        for (int off = 1; off <= 2; off <<= 1) {
            float m2 = __shfl_xor(m, off, 64);
            float s2 = __shfl_xor(s, off, 64);
            float nm = fmaxf(m, m2);
            s = s * EXP2F(m - nm) + s2 * EXP2F(m2 - nm);
            m = nm;
        }
        if (c == 0) {
            float res = -EPS_LN2 * (m - 10.0f + LOG2F(s));
            float newv = 0.5f * (myold + res);
            atomicExch(&g_seq[k + 1][p][b][i], newv);   // publish memory-side
            myold = newv;
        }

        if (k == 3) {
            // fine-list build from the coarse list, pre-update h (same anchor
            // as round 5/8). m = true row max.
            float thr = m - MARGIN_T;
            int cl = 0;
            for (int kk = 0; kk < nstep; ++kk) {
                int base = kk * 16 + c * 4;
                uint4 u = cd4[kk * 4 + c];
                unsigned w[4] = {u.x, u.y, u.z, u.w};
                #pragma unroll
                for (int o = 0; o < 4; ++o) {
                    if (base + o < cnt) {
                        __half hh;
                        *reinterpret_cast<unsigned short*>(&hh) = (unsigned short)(w[o] & 0xffffu);
                        float tv = fmaf(__half2float(hh), -K_SCALE, h2[(w[o] >> 16) & 1023]);
                        if (tv >= thr) ++cl;
                    }
                }
            }
            int g0 = lane & ~3;
            int c0 = __shfl(cl, g0 + 0, 64);
            int c1 = __shfl(cl, g0 + 1, 64);
            int c2 = __shfl(cl, g0 + 2, 64);
            int c3 = __shfl(cl, g0 + 3, 64);
            int excl = ((c >= 1) ? c0 : 0) + ((c >= 2) ? c1 : 0) + ((c >= 3) ? c2 : 0);
            int total = c0 + c1 + c2 + c3;
            if (c == 0) g_cnt_f[rowid] = (unsigned)(total < CAPF ? total : CAPF);
            unsigned* dst = &g_cand_f[rowid * CAPF];
            int slot = excl;
            for (int kk = 0; kk < nstep; ++kk) {
                int base = kk * 16 + c * 4;
                uint4 u = cd4[kk * 4 + c];
                unsigned w[4] = {u.x, u.y, u.z, u.w};
                #pragma unroll
                for (int o = 0; o < 4; ++o) {
                    if (base + o < cnt) {
                        __half hh;
                        *reinterpret_cast<unsigned short*>(&hh) = (unsigned short)(w[o] & 0xffffu);
                        float tv = fmaf(__half2float(hh), -K_SCALE, h2[(w[o] >> 16) & 1023]);
                        if (tv >= thr) {
                            if (slot < CAPF) dst[slot] = w[o];
                            ++slot;
                        }
                    }
                }
            }
        }

        if (k < NPERS - 1) {
            // per-component barrier: all writes drained by __syncthreads
            // (vmcnt(0)), arrival counter is device-scope (memory-side).
            __syncthreads();
            if (tid == 0) {
                unsigned old = atomicAdd(&g_bar[comp][k], 1u);
                if (old + 1u < nb) {
                    while (atomicAdd(&g_bar[comp][k], 0u) < nb)
                        __builtin_amdgcn_s_sleep(1);
                }
            }
            __syncthreads();
        }
    }
}

__global__ __launch_bounds__(256) void epilogue_kernel(float* __restrict__ out) {
    int tid = threadIdx.x;
    const float* f = &g_seq[NPERS][0][0][0];
    const float* g = &g_seq[NPERS][1][0][0];
    const float* pp = &g_seq[NPERS][2][0][0];
    const float* q = &g_seq[NPERS][3][0][0];
    float acc = 0.0f;
    for (int idx = tid; idx < BATCH * NN; idx += 256) {
        acc += (f[idx] - pp[idx]) + (g[idx] - q[idx]);
    }
    float macc = (tid < 128) ? g_mse_part[tid] : 0.0f;
    #pragma unroll
    for (int off = 32; off; off >>= 1) {
        acc += __shfl_xor(acc, off, 64);
        macc += __shfl_xor(macc, off, 64);
    }
    __shared__ float red[4], redm[4];
    int lane = tid & 63, wid = tid >> 6;
    if (lane == 0) { red[wid] = acc; redm[wid] = macc; }
    __syncthreads();
    if (tid == 0) {
        float ot = (red[0] + red[1] + red[2] + red[3]) / (float)(BATCH * NN);
        float mse = (redm[0] + redm[1] + redm[2] + redm[3]) / (float)(BATCH * NN * CDIM);
        out[0] = mse + ot;
        out[1] = mse;
        out[2] = ot;
    }
}

extern "C" void kernel_launch(void* const* d_in, const int* in_sizes, int n_in,
                              void* d_out, int out_size, void* d_ws, size_t ws_size,
                              hipStream_t stream) {
    const float* pred = (const float*)d_in[0];
    const float* gt   = (const float*)d_in[1];
    float* out = (float*)d_out;

    init_mse_kernel<<<128, 256, 0, stream>>>(pred, gt);
    // cost + fused t=0 (writes g_pot[1])
    cost_kernel<<<4 * BATCH * 64, 256, 0, stream>>>(pred, gt);
    // t=1 dense: reads g_pot[1], writes g_pot[0]
    iter_kernel_t<false><<<4 * BATCH * 64, 256, 0, stream>>>(1);
    // t=2 dense + coarse build: reads g_pot[0], writes g_seq[0]
    iter_kernel_t<true ><<<4 * BATCH * 64, 256, 0, stream>>>(0);
    // t=3..49 in one persistent launch (coarse k<=3, fine build at k==3)
    persist_kernel<<<4 * BATCH * 16, 256, 0, stream>>>();
    epilogue_kernel<<<1, 256, 0, stream>>>(out);
}